// Round 4
// baseline (798.442 us; speedup 1.0000x reference)
//
#include <hip/hip_runtime.h>
#include <math.h>

typedef __attribute__((ext_vector_type(8))) short bf16x8;
typedef __attribute__((ext_vector_type(4))) float f32x4;
typedef __attribute__((ext_vector_type(4))) unsigned u32x4;

// ---------------- workspace layout (u32 offsets) ----------------
// h1p : [16][128][130][132] packed u32 (halo-padded)  = 35,143,680
// h2p : [16][256][66][68]   packed u32 (halo-padded)  = 18,382,848
// wp2 : [256][2048] packed  = 524,288
// wp3 : [64][3072]  packed (kw padded to 4, zeros)    = 196,608
#define H1P_OFF  0ull
#define H2P_OFF  35143680ull
#define WP2_OFF  53526528ull
#define WP3_OFF  54050816ull
#define EN_OFF   54247424ull
#define HIST_OFF 54247936ull
#define SSE_OFF  54248448ull

__device__ inline unsigned short f2bf(float f) {
  unsigned u = __builtin_bit_cast(unsigned, f);
  return (unsigned short)((u + 0x7fffu + ((u >> 16) & 1u)) >> 16);  // RNE
}
__device__ inline float bf2f(unsigned short h) {
  return __builtin_bit_cast(float, (unsigned)h << 16);
}
__device__ inline unsigned packsplit(float v) {
  unsigned short h = f2bf(v);
  unsigned short l = f2bf(v - bf2f(h));
  return (unsigned)h | ((unsigned)l << 16);
}
__device__ inline int swz(int row, int g) {  // byte offset in a [rows][32 u32] tile
  return ((row << 7) + (g << 4)) ^ ((row & 7) << 4);
}
#define SEL_HI 0x05040100u
#define SEL_LO 0x07060302u
__device__ inline bf16x8 mkfrag(const u32x4 p, const u32x4 q, unsigned sel) {
  u32x4 r;
  r[0] = __builtin_amdgcn_perm(p[1], p[0], sel);
  r[1] = __builtin_amdgcn_perm(p[3], p[2], sel);
  r[2] = __builtin_amdgcn_perm(q[1], q[0], sel);
  r[3] = __builtin_amdgcn_perm(q[3], q[2], sel);
  return __builtin_bit_cast(bf16x8, r);
}

// ================= weight prep =================
__global__ void pack_w2_k(const float* __restrict__ w, unsigned* __restrict__ wp) {
  int i = blockIdx.x * 256 + threadIdx.x;
  if (i < 524288) wp[i] = packsplit(w[i]);   // layout already [co][ci*16+kh*4+kw]
}
__global__ void pack_w3_k(const float* __restrict__ w, unsigned* __restrict__ wp) {
  int i = blockIdx.x * 256 + threadIdx.x;
  if (i >= 196608) return;
  int co = i / 3072, r = i - co * 3072;
  int ci = r / 12, rb = r - ci * 12, kh = rb >> 2, kw = rb & 3;
  wp[i] = (kw < 3) ? packsplit(w[((co * 256 + ci) * 3 + kh) * 3 + kw]) : 0u;
}

// ================= halo zeroing for padded activation planes =================
__global__ void halo_k(unsigned* __restrict__ h1p, unsigned* __restrict__ h2p) {
  int i = blockIdx.x * 256 + threadIdx.x;
  if (i < 2048 * 520) {           // h1p: 2048 planes x 520 halo cells
    int p = i / 520, c = i - p * 520; int r, cc;
    if (c < 132)      { r = 0;   cc = c; }
    else if (c < 264) { r = 129; cc = c - 132; }
    else if (c < 392) { r = c - 264 + 1; cc = 0; }
    else              { r = c - 392 + 1; cc = 129; }
    h1p[(size_t)p * 130 * 132 + r * 132 + cc] = 0u;
  } else {
    int j = i - 2048 * 520;
    if (j >= 4096 * 328) return;  // h2p: 4096 planes x 328 halo cells
    int p = j / 328, c = j - p * 328; int r, cc;
    if (c < 68)       { r = 0;  cc = c; }
    else if (c < 136) { r = 65; cc = c - 68; }
    else { int c2 = c - 136; int which = c2 >> 6; r = 1 + (c2 & 63);
           cc = (which == 0) ? 0 : (which == 1 ? 65 : 66); }
    h2p[(size_t)p * 66 * 68 + r * 68 + cc] = 0u;
  }
}

// ================= conv1: 3->128, 4x4 s2 p1, fp32 vector, padded packed out ====
__global__ __launch_bounds__(256) void conv1_k(const float* __restrict__ x,
                                               const float* __restrict__ w,
                                               const float* __restrict__ bias,
                                               unsigned* __restrict__ out) {
  const int tx = threadIdx.x, ty = threadIdx.y;
  const int tile_x = blockIdx.x, tile_y = blockIdx.y, b = blockIdx.z;
  __shared__ float xs[3][34][35];
  const int tid = ty * 16 + tx;
  const int iy0 = tile_y * 32 - 1, ix0 = tile_x * 32 - 1;
  for (int idx = tid; idx < 3 * 1156; idx += 256) {
    int ci = idx / 1156; int rem = idx - ci * 1156;
    int r = rem / 34;    int c = rem - r * 34;
    int iy = iy0 + r, ix = ix0 + c;
    float v = 0.f;
    if (iy >= 0 && iy < 256 && ix >= 0 && ix < 256)
      v = x[((b * 3 + ci) * 256 + iy) * 256 + ix];
    xs[ci][r][c] = v;
  }
  __syncthreads();
  float p[48];
#pragma unroll
  for (int ci = 0; ci < 3; ++ci)
#pragma unroll
    for (int kh = 0; kh < 4; ++kh)
#pragma unroll
      for (int kw = 0; kw < 4; ++kw)
        p[ci * 16 + kh * 4 + kw] = xs[ci][2 * ty + kh][2 * tx + kw];
  const int Y = tile_y * 16 + ty, X = tile_x * 16 + tx;
  for (int co = 0; co < 128; ++co) {
    float acc = bias[co];
#pragma unroll
    for (int t = 0; t < 48; ++t) acc += p[t] * w[co * 48 + t];  // uniform -> s_load
    float v = acc > 0.f ? acc : 0.f;
    out[((size_t)(b * 128 + co) * 130 + (Y + 1)) * 132 + (X + 1)] = packsplit(v);
  }
}

// ====== pipelined implicit-GEMM conv, split-bf16 MFMA, B in registers =========
// A (activations) LDS-broadcast, double-buffered, swizzled; B (weights) loaded
// global->reg per wave (L2-resident). One barrier per K-step, counted waits
// are compiler-managed via register deps.
// NWX: wave x-split (1 or 2), NWC: wave co-split (NWX*NWC==4). M = 64*NWX rows.
template <int IC, int KHW, int OC, int IHP, int IWP, int S, int NWX, int NWC,
          int OSR, int OSP, int OPAD, bool SPLIT_OUT>
__global__ __launch_bounds__(256, 3) void convmm_k(const unsigned* __restrict__ inp,
                                                   const unsigned* __restrict__ wp,
                                                   const float* __restrict__ bias,
                                                   unsigned* __restrict__ outp,
                                                   float* __restrict__ outf) {
  constexpr int K = IC * KHW;
  constexpr int KSTEPS = K / 32;
  constexpr int NFRAG = OC / NWC / 16;     // n-frags per wave
  constexpr int MR = 64 * NWX;             // A-tile rows
  constexpr int CELLS = MR / 32;           // staged 16B cells per thread (2 or 4)
  constexpr int ABYTES = MR * 128;
  constexpr int LOG2NWX = (NWX == 2) ? 1 : 0;
  constexpr int YBITS = 6 - LOG2NWX;

  __shared__ char smem[2 * ABYTES];

  const int tid = threadIdx.x, l = tid & 63, wv = tid >> 6;
  const int bb = blockIdx.x >> YBITS;
  const int y0 = blockIdx.x & ((1 << YBITS) - 1);
  const int rsel = l & 15, g0 = (l >> 4) * 2, ko = (l >> 4) * 8;
  const int mbase = (wv & (NWX - 1)) * 64;
  const int nbase = (wv >> LOG2NWX) * (OC / NWC);

  // ---- A staging assignment: thread covers CELLS (row, quad) 16B cells ----
  const int arow = tid & (MR - 1);
  int qs[CELLS];
  const unsigned* abase[CELLS];   // conv2 (KHW==16): rolling pointers
#pragma unroll
  for (int c = 0; c < CELLS; ++c) {
    if constexpr (NWX == 1) qs[c] = (tid >> 6) + c * 4;       // q in 0..7
    else                    qs[c] = (tid >> 7) * 4 + c;       // q in 0..7
    if constexpr (KHW == 16) {
      int ci0 = qs[c] >> 2, kh = qs[c] & 3;
      abase[c] = inp + (((size_t)bb * IC + ci0) * IHP + (S * y0 + kh)) * IWP + S * arow;
    }
  }
  const int awb[2] = { (arow << 7) + ((qs[0] ^ (arow & 7)) << 4),
                       (arow << 7) + ((qs[CELLS - 1] ^ (arow & 7)) << 4) };

  f32x4 acc[NFRAG][4];
#pragma unroll
  for (int nf = 0; nf < NFRAG; ++nf)
#pragma unroll
    for (int xf = 0; xf < 4; ++xf) acc[nf][xf] = (f32x4){0.f, 0.f, 0.f, 0.f};

  unsigned av[CELLS][4];

  auto loadA = [&](int ks) {
#pragma unroll
    for (int c = 0; c < CELLS; ++c) {
      if constexpr (KHW == 16) {
        const unsigned* p = abase[c];
        av[c][0] = p[0]; av[c][1] = p[1]; av[c][2] = p[2]; av[c][3] = p[3];
        abase[c] += (size_t)2 * IHP * IWP;      // ci += 2 per step, kh invariant
      } else {                                   // KHW == 12 (conv3)
        int k = ks * 32 + qs[c] * 4;
        int ci = (k * 5462) >> 16;               // k/12, exact for k<3072
        int rb = k - ci * 12;
        int kh = rb >> 2;
        int yl = arow >> 6, x = arow & 63;
        const unsigned* p = inp + (((size_t)bb * IC + ci) * IHP + (y0 * 2 + yl + kh)) * IWP + x;
        av[c][0] = p[0]; av[c][1] = p[1]; av[c][2] = p[2]; av[c][3] = p[3];
      }
    }
  };
  auto writeA = [&](int buf) {
    char* base = smem + buf * ABYTES;
#pragma unroll
    for (int c = 0; c < CELLS; ++c) {
      int wb = (arow << 7) + ((qs[c] ^ (arow & 7)) << 4);
      *(u32x4*)(base + wb) = *(u32x4*)&av[c][0];
    }
    (void)awb;
  };

  // ---- prologue: stage tile 0 ----
  loadA(0);
  writeA(0);
  asm volatile("s_waitcnt lgkmcnt(0)" ::: "memory");
  __builtin_amdgcn_s_barrier();
  asm volatile("" ::: "memory");

#pragma unroll 1
  for (int ks = 0; ks < KSTEPS; ++ks) {
    const int cur = ks & 1;
    const bool has = (ks + 1 < KSTEPS);
    // ---- B: global -> reg (L2-resident weights), consumed this step ----
    u32x4 br[NFRAG][2];
#pragma unroll
    for (int nf = 0; nf < NFRAG; ++nf) {
      const unsigned* bp = wp + (size_t)(nbase + nf * 16 + rsel) * K + ks * 32 + ko;
      br[nf][0] = *(const u32x4*)bp;
      br[nf][1] = *(const u32x4*)(bp + 4);
    }
    // ---- A: issue next-step global loads (latency hidden under MFMAs) ----
    if (has) loadA(ks + 1);
    // ---- A frags from LDS ----
    const char* bA = smem + cur * ABYTES;
    u32x4 ar[4][2];
#pragma unroll
    for (int xf = 0; xf < 4; ++xf) {
      int row = mbase + xf * 16 + rsel;
      ar[xf][0] = *(const u32x4*)(bA + swz(row, g0));
      ar[xf][1] = *(const u32x4*)(bA + swz(row, g0 + 1));
    }
    bf16x8 ah[4], al[4];
#pragma unroll
    for (int xf = 0; xf < 4; ++xf) {
      ah[xf] = mkfrag(ar[xf][0], ar[xf][1], SEL_HI);
      al[xf] = mkfrag(ar[xf][0], ar[xf][1], SEL_LO);
    }
#pragma unroll
    for (int nf = 0; nf < NFRAG; ++nf) {
      bf16x8 wh = mkfrag(br[nf][0], br[nf][1], SEL_HI);
      bf16x8 wl = mkfrag(br[nf][0], br[nf][1], SEL_LO);
#pragma unroll
      for (int xf = 0; xf < 4; ++xf) {
        acc[nf][xf] = __builtin_amdgcn_mfma_f32_16x16x32_bf16(wh, ah[xf], acc[nf][xf], 0, 0, 0);
        acc[nf][xf] = __builtin_amdgcn_mfma_f32_16x16x32_bf16(wh, al[xf], acc[nf][xf], 0, 0, 0);
        acc[nf][xf] = __builtin_amdgcn_mfma_f32_16x16x32_bf16(wl, ah[xf], acc[nf][xf], 0, 0, 0);
      }
    }
    // ---- fence keeps the A-write (and its av vmcnt wait) after the MFMAs ----
    asm volatile("" ::: "memory");
    if (has) writeA(cur ^ 1);
    asm volatile("s_waitcnt lgkmcnt(0)" ::: "memory");
    __builtin_amdgcn_s_barrier();
    asm volatile("" ::: "memory");
  }

  // ---- epilogue: D col = lane&15 -> m, row = (lane>>4)*4+r -> co ----
#pragma unroll
  for (int nf = 0; nf < NFRAG; ++nf) {
    int n0 = nbase + nf * 16 + (l >> 4) * 4;
#pragma unroll
    for (int xf = 0; xf < 4; ++xf) {
      int m = mbase + xf * 16 + rsel;
      int yl = m >> 6, xo = m & 63;
      int yout = y0 * NWX + yl;
#pragma unroll
      for (int r = 0; r < 4; ++r) {
        float v = acc[nf][xf][r] + bias[n0 + r];
        if constexpr (SPLIT_OUT) {  // conv2: ReLU + packed padded store
          if (v < 0.f) v = 0.f;
          outp[((size_t)bb * OC + n0 + r) * OSP + (size_t)(yout + OPAD) * OSR + (xo + OPAD)] =
              packsplit(v);
        } else {                    // conv3: fp32 dense z
          outf[((size_t)bb * OC + n0 + r) * OSP + (size_t)yout * OSR + xo] = v;
        }
      }
    }
  }
}

// ================= embedding norms =================
__global__ void enorm_k(const float* __restrict__ emb, float* __restrict__ enorm) {
  int k = threadIdx.x;
  if (k < 512) {
    float s = 0.f;
#pragma unroll
    for (int d = 0; d < 64; ++d) { float e = emb[k * 64 + d]; s += e * e; }
    enorm[k] = s;
  }
}

// ================= VQ: argmin + quantize(in-place) + hist + sse =================
__global__ __launch_bounds__(256) void vq_k(float* __restrict__ zq,
                                            const float* __restrict__ emb,
                                            const float* __restrict__ enorm,
                                            unsigned* __restrict__ hist,
                                            float* __restrict__ gsse) {
  const int n = blockIdx.x * 256 + threadIdx.x;
  __shared__ unsigned hcnt[512];
  for (int i = threadIdx.x; i < 512; i += 256) hcnt[i] = 0;
  __syncthreads();
  float z[64];
  const float4* zp4 = reinterpret_cast<const float4*>(&zq[(size_t)n * 64]);
#pragma unroll
  for (int d4 = 0; d4 < 16; ++d4) {
    float4 v = zp4[d4];
    z[d4 * 4 + 0] = v.x; z[d4 * 4 + 1] = v.y; z[d4 * 4 + 2] = v.z; z[d4 * 4 + 3] = v.w;
  }
  float best = 1e30f; int bidx = 0;
  for (int k = 0; k < 512; ++k) {
    float dot = 0.f;
    const float* ep = &emb[k * 64];  // uniform -> s_load
#pragma unroll
    for (int d = 0; d < 64; ++d) dot += z[d] * ep[d];
    float dist = enorm[k] - 2.f * dot;
    if (dist < best) { best = dist; bidx = k; }  // strict < : first-min == argmin
  }
  atomicAdd(&hcnt[bidx], 1u);
  float sse = 0.f;
  float4* op4 = reinterpret_cast<float4*>(&zq[(size_t)n * 64]);
  const float4* eb4 = reinterpret_cast<const float4*>(&emb[bidx * 64]);
#pragma unroll
  for (int d4 = 0; d4 < 16; ++d4) {
    float4 q = eb4[d4];
    float dx = q.x - z[d4 * 4 + 0], dy = q.y - z[d4 * 4 + 1];
    float dz = q.z - z[d4 * 4 + 2], dw = q.w - z[d4 * 4 + 3];
    sse += dx * dx + dy * dy + dz * dz + dw * dw;
    op4[d4] = q;
  }
#pragma unroll
  for (int off = 32; off > 0; off >>= 1) sse += __shfl_down(sse, off, 64);
  if ((threadIdx.x & 63) == 0) atomicAdd(gsse, sse);
  __syncthreads();
  for (int i = threadIdx.x; i < 512; i += 256)
    if (hcnt[i]) atomicAdd(&hist[i], hcnt[i]);
}

// ================= finalize =================
__global__ void fin_k(const unsigned* __restrict__ hist,
                      const float* __restrict__ gsse,
                      float* __restrict__ out) {
  __shared__ float red[512];
  int t = threadIdx.x;
  float p = (float)hist[t] * (1.f / 65536.f);
  red[t] = p * logf(p + 1e-10f);
  __syncthreads();
  for (int s = 256; s > 0; s >>= 1) {
    if (t < s) red[t] += red[t + s];
    __syncthreads();
  }
  if (t == 0) {
    out[4194304] = 1.25f * gsse[0] * (1.f / 4194304.f);
    out[4194305] = expf(-red[0]);
  }
}

extern "C" void kernel_launch(void* const* d_in, const int* in_sizes, int n_in,
                              void* d_out, int out_size, void* d_ws, size_t ws_size,
                              hipStream_t stream) {
  const float* x   = (const float*)d_in[0];
  const float* w1  = (const float*)d_in[1];
  const float* b1  = (const float*)d_in[2];
  const float* w2  = (const float*)d_in[3];
  const float* b2  = (const float*)d_in[4];
  const float* w3  = (const float*)d_in[5];
  const float* b3  = (const float*)d_in[6];
  const float* emb = (const float*)d_in[7];
  // decoder weights unused: reference output ignores x_recon

  float* out = (float*)d_out;
  unsigned* wsu = (unsigned*)d_ws;
  unsigned* h1p = wsu + H1P_OFF;
  unsigned* h2p = wsu + H2P_OFF;
  unsigned* wp2 = wsu + WP2_OFF;
  unsigned* wp3 = wsu + WP3_OFF;
  float* enorm = (float*)(wsu + EN_OFF);
  unsigned* hist = wsu + HIST_OFF;
  float* gsse = (float*)(wsu + SSE_OFF);

  hipMemsetAsync(wsu + HIST_OFF, 0, (512 + 1) * sizeof(unsigned), stream);

  pack_w2_k<<<dim3(2048), dim3(256), 0, stream>>>(w2, wp2);
  pack_w3_k<<<dim3(768),  dim3(256), 0, stream>>>(w3, wp3);
  halo_k<<<dim3(9408), dim3(256), 0, stream>>>(h1p, h2p);
  enorm_k<<<dim3(1), dim3(512), 0, stream>>>(emb, enorm);

  conv1_k<<<dim3(8, 8, 16), dim3(16, 16), 0, stream>>>(x, w1, b1, h1p);
  // conv2: 128->256, 4x4 s2 p1 ; M=64 (NWX=1,NWC=4), out h2p [66][68] packed+ReLU
  convmm_k<128, 16, 256, 130, 132, 2, 1, 4, 68, 4488, 1, true>
      <<<dim3(1024), dim3(256), 0, stream>>>(h1p, wp2, b2, h2p, nullptr);
  // conv3: 256->64, 3x3 s1 p1 (kw padded to 4) ; M=128 (NWX=2,NWC=2), fp32 z -> d_out
  convmm_k<256, 12, 64, 66, 68, 1, 2, 2, 64, 4096, 0, false>
      <<<dim3(512), dim3(256), 0, stream>>>(h2p, wp3, b3, nullptr, out);

  vq_k<<<dim3(256), dim3(256), 0, stream>>>(out, emb, enorm, hist, gsse);
  fin_k<<<dim3(1), dim3(512), 0, stream>>>(hist, gsse, out);
}

// Round 5
// 616.924 us; speedup vs baseline: 1.2942x; 1.2942x over previous
//
#include <hip/hip_runtime.h>
#include <math.h>

typedef __attribute__((ext_vector_type(8))) short bf16x8;
typedef __attribute__((ext_vector_type(4))) float f32x4;
typedef __attribute__((ext_vector_type(4))) unsigned u32x4;

// ---------------- workspace layout (u32 offsets) ----------------
// h1p : [16][128][130][132] packed u32 (halo-padded)  = 35,143,680
// h2p : [16][256][66][68]   packed u32 (halo-padded)  = 18,382,848
// wq2 : lane-contiguous repack, 524,288 u32
// wq3 : lane-contiguous repack, 196,608 u32
#define H1P_OFF  0ull
#define H2P_OFF  35143680ull
#define WP2_OFF  53526528ull
#define WP3_OFF  54050816ull
#define EN_OFF   54247424ull
#define HIST_OFF 54247936ull
#define SSE_OFF  54248448ull

__device__ inline unsigned short f2bf(float f) {
  unsigned u = __builtin_bit_cast(unsigned, f);
  return (unsigned short)((u + 0x7fffu + ((u >> 16) & 1u)) >> 16);  // RNE
}
__device__ inline float bf2f(unsigned short h) {
  return __builtin_bit_cast(float, (unsigned)h << 16);
}
__device__ inline unsigned packsplit(float v) {
  unsigned short h = f2bf(v);
  unsigned short l = f2bf(v - bf2f(h));
  return (unsigned)h | ((unsigned)l << 16);
}
__device__ inline int swz(int row, int g) {  // byte offset in a [rows][32 u32] tile
  return ((row << 7) + (g << 4)) ^ ((row & 7) << 4);
}
#define SEL_HI 0x05040100u
#define SEL_LO 0x07060302u
__device__ inline bf16x8 mkfrag(const u32x4 p, const u32x4 q, unsigned sel) {
  u32x4 r;
  r[0] = __builtin_amdgcn_perm(p[1], p[0], sel);
  r[1] = __builtin_amdgcn_perm(p[3], p[2], sel);
  r[2] = __builtin_amdgcn_perm(q[1], q[0], sel);
  r[3] = __builtin_amdgcn_perm(q[3], q[2], sel);
  return __builtin_bit_cast(bf16x8, r);
}

// ======= weight repack: lane-contiguous per (ks, frag, j) 1KB blocks =========
// element (row = fg*16 + (l&15), k = ks*32 + (l>>4)*8 + j*4 + e) stored at
// i = (((ks*FGTOT + fg)*2 + j)*64 + l)*4 + e  -> each frag b128 load is one
// fully-coalesced 1KB burst.
__global__ void pack_wq2_k(const float* __restrict__ w, unsigned* __restrict__ wq) {
  int i = blockIdx.x * 256 + threadIdx.x;
  if (i >= 524288) return;
  int e = i & 3, l = (i >> 2) & 63, j = (i >> 8) & 1, fg = (i >> 9) & 15, ks = i >> 13;
  int row = fg * 16 + (l & 15);
  int k = ks * 32 + (l >> 4) * 8 + j * 4 + e;     // k == ci*16+kh*4+kw (w2 native)
  wq[i] = packsplit(w[row * 2048 + k]);
}
__global__ void pack_wq3_k(const float* __restrict__ w, unsigned* __restrict__ wq) {
  int i = blockIdx.x * 256 + threadIdx.x;
  if (i >= 196608) return;
  int e = i & 3, l = (i >> 2) & 63, j = (i >> 8) & 1, fg = (i >> 9) & 3, ks = i >> 11;
  int row = fg * 16 + (l & 15);
  int k = ks * 32 + (l >> 4) * 8 + j * 4 + e;     // KHW padded to 12 (kw 0..3)
  int ci = k / 12, rb = k - ci * 12, kh = rb >> 2, kw = rb & 3;
  wq[i] = (kw < 3) ? packsplit(w[((row * 256 + ci) * 3 + kh) * 3 + kw]) : 0u;
}

// ================= halo zeroing for padded activation planes =================
__global__ void halo_k(unsigned* __restrict__ h1p, unsigned* __restrict__ h2p) {
  int i = blockIdx.x * 256 + threadIdx.x;
  if (i < 2048 * 520) {           // h1p: 2048 planes x 520 halo cells
    int p = i / 520, c = i - p * 520; int r, cc;
    if (c < 132)      { r = 0;   cc = c; }
    else if (c < 264) { r = 129; cc = c - 132; }
    else if (c < 392) { r = c - 264 + 1; cc = 0; }
    else              { r = c - 392 + 1; cc = 129; }
    h1p[(size_t)p * 130 * 132 + r * 132 + cc] = 0u;
  } else {
    int j = i - 2048 * 520;
    if (j >= 4096 * 328) return;  // h2p: 4096 planes x 328 halo cells
    int p = j / 328, c = j - p * 328; int r, cc;
    if (c < 68)       { r = 0;  cc = c; }
    else if (c < 136) { r = 65; cc = c - 68; }
    else { int c2 = c - 136; int which = c2 >> 6; r = 1 + (c2 & 63);
           cc = (which == 0) ? 0 : (which == 1 ? 65 : 66); }
    h2p[(size_t)p * 66 * 68 + r * 68 + cc] = 0u;
  }
}

// ================= conv1: 3->128, 4x4 s2 p1, fp32 vector, padded packed out ====
__global__ __launch_bounds__(256) void conv1_k(const float* __restrict__ x,
                                               const float* __restrict__ w,
                                               const float* __restrict__ bias,
                                               unsigned* __restrict__ out) {
  const int tx = threadIdx.x, ty = threadIdx.y;
  const int tile_x = blockIdx.x, tile_y = blockIdx.y, b = blockIdx.z;
  __shared__ float xs[3][34][35];
  const int tid = ty * 16 + tx;
  const int iy0 = tile_y * 32 - 1, ix0 = tile_x * 32 - 1;
  for (int idx = tid; idx < 3 * 1156; idx += 256) {
    int ci = idx / 1156; int rem = idx - ci * 1156;
    int r = rem / 34;    int c = rem - r * 34;
    int iy = iy0 + r, ix = ix0 + c;
    float v = 0.f;
    if (iy >= 0 && iy < 256 && ix >= 0 && ix < 256)
      v = x[((b * 3 + ci) * 256 + iy) * 256 + ix];
    xs[ci][r][c] = v;
  }
  __syncthreads();
  float p[48];
#pragma unroll
  for (int ci = 0; ci < 3; ++ci)
#pragma unroll
    for (int kh = 0; kh < 4; ++kh)
#pragma unroll
      for (int kw = 0; kw < 4; ++kw)
        p[ci * 16 + kh * 4 + kw] = xs[ci][2 * ty + kh][2 * tx + kw];
  const int Y = tile_y * 16 + ty, X = tile_x * 16 + tx;
  for (int co = 0; co < 128; ++co) {
    float acc = bias[co];
#pragma unroll
    for (int t = 0; t < 48; ++t) acc += p[t] * w[co * 48 + t];  // uniform -> s_load
    float v = acc > 0.f ? acc : 0.f;
    out[((size_t)(b * 128 + co) * 130 + (Y + 1)) * 132 + (X + 1)] = packsplit(v);
  }
}

// ====== pipelined implicit-GEMM conv, split-bf16 MFMA =========================
// A: LDS-broadcast, double-buffered, swizzled (shared by all waves).
// B: lane-contiguous repacked weights, global->reg, REGISTER double-buffered
//    (brA/brB static names, ks-loop unrolled x2) -> latency hidden under MFMAs.
// One __syncthreads per K-step; all waitcnts compiler-managed via reg deps.
template <int IC, int KHW, int OC, int IHP, int IWP, int S, int NWX, int NWC,
          int OSR, int OSP, int OPAD, bool SPLIT_OUT>
__global__ __launch_bounds__(256, 2) void convmm_k(const unsigned* __restrict__ inp,
                                                   const unsigned* __restrict__ wq,
                                                   const float* __restrict__ bias,
                                                   unsigned* __restrict__ outp,
                                                   float* __restrict__ outf) {
  constexpr int K = IC * KHW;
  constexpr int KSTEPS = K / 32;
  constexpr int FGTOT = OC / 16;
  constexpr int NFRAG = OC / NWC / 16;     // n-frags per wave
  constexpr int MR = 64 * NWX;             // A-tile rows
  constexpr int CELLS = MR / 32;           // staged 16B cells per thread
  constexpr int ABYTES = MR * 128;
  constexpr int LOG2NWX = (NWX == 2) ? 1 : 0;
  constexpr int YBITS = 6 - LOG2NWX;

  __shared__ char smem[2 * ABYTES];

  const int tid = threadIdx.x, l = tid & 63, wv = tid >> 6;
  const int bb = blockIdx.x >> YBITS;
  const int y0 = blockIdx.x & ((1 << YBITS) - 1);
  const int rsel = l & 15, g0 = (l >> 4) * 2;
  const int mbase = (wv & (NWX - 1)) * 64;
  const int fgbase = (wv >> LOG2NWX) * NFRAG;
  const int nbase = fgbase * 16;

  // ---- A staging assignment: thread covers CELLS (row, quad) 16B cells ----
  const int arow = tid & (MR - 1);
  int qs[CELLS];
  const unsigned* abase[CELLS];   // conv2 (KHW==16): rolling pointers
#pragma unroll
  for (int c = 0; c < CELLS; ++c) {
    if constexpr (NWX == 1) qs[c] = (tid >> 6) + c * 4;       // q in 0..7
    else                    qs[c] = (tid >> 7) * 4 + c;       // q in 0..7
    if constexpr (KHW == 16) {
      int ci0 = qs[c] >> 2, kh = qs[c] & 3;
      abase[c] = inp + (((size_t)bb * IC + ci0) * IHP + (S * y0 + kh)) * IWP + S * arow;
    }
  }

  f32x4 acc[NFRAG][4];
#pragma unroll
  for (int nf = 0; nf < NFRAG; ++nf)
#pragma unroll
    for (int xf = 0; xf < 4; ++xf) acc[nf][xf] = (f32x4){0.f, 0.f, 0.f, 0.f};

  unsigned av[CELLS][4];
  u32x4 brA[NFRAG][2], brB[NFRAG][2];

  auto loadA = [&](int ks) {
#pragma unroll
    for (int c = 0; c < CELLS; ++c) {
      if constexpr (KHW == 16) {
        const unsigned* p = abase[c];
        av[c][0] = p[0]; av[c][1] = p[1]; av[c][2] = p[2]; av[c][3] = p[3];
        abase[c] += (size_t)2 * IHP * IWP;      // ci += 2 per step, kh invariant
      } else {                                   // KHW == 12 (conv3)
        int k = ks * 32 + qs[c] * 4;
        int ci = (k * 5462) >> 16;               // k/12, exact for k<3072
        int rb = k - ci * 12;
        int kh = rb >> 2;
        int yl = arow >> 6, x = arow & 63;
        const unsigned* p = inp + (((size_t)bb * IC + ci) * IHP + (y0 * 2 + yl + kh)) * IWP + x;
        av[c][0] = p[0]; av[c][1] = p[1]; av[c][2] = p[2]; av[c][3] = p[3];
      }
    }
  };
  auto writeA = [&](int buf) {
    char* base = smem + buf * ABYTES;
#pragma unroll
    for (int c = 0; c < CELLS; ++c) {
      int wb = (arow << 7) + ((qs[c] ^ (arow & 7)) << 4);
      *(u32x4*)(base + wb) = *(u32x4*)&av[c][0];
    }
  };
  auto loadB = [&](int ks, u32x4 (&br)[NFRAG][2]) {
#pragma unroll
    for (int nf = 0; nf < NFRAG; ++nf)
#pragma unroll
      for (int j = 0; j < 2; ++j)
        br[nf][j] = *(const u32x4*)(wq + (((size_t)((ks * FGTOT + fgbase + nf) * 2 + j)) << 8)
                                       + (l << 2));
  };
  auto step = [&](int ks, u32x4 (&cur)[NFRAG][2], u32x4 (&nxt)[NFRAG][2]) {
    const bool has = (ks + 1 < KSTEPS);
    if (has) { loadB(ks + 1, nxt); loadA(ks + 1); }   // issue early, consume late
    const char* bA = smem + (ks & 1) * ABYTES;
    u32x4 ar[4][2];
#pragma unroll
    for (int xf = 0; xf < 4; ++xf) {
      int row = mbase + xf * 16 + rsel;
      ar[xf][0] = *(const u32x4*)(bA + swz(row, g0));
      ar[xf][1] = *(const u32x4*)(bA + swz(row, g0 + 1));
    }
    bf16x8 ah[4], al[4];
#pragma unroll
    for (int xf = 0; xf < 4; ++xf) {
      ah[xf] = mkfrag(ar[xf][0], ar[xf][1], SEL_HI);
      al[xf] = mkfrag(ar[xf][0], ar[xf][1], SEL_LO);
    }
#pragma unroll
    for (int nf = 0; nf < NFRAG; ++nf) {
      bf16x8 wh = mkfrag(cur[nf][0], cur[nf][1], SEL_HI);
      bf16x8 wl = mkfrag(cur[nf][0], cur[nf][1], SEL_LO);
#pragma unroll
      for (int xf = 0; xf < 4; ++xf) {
        acc[nf][xf] = __builtin_amdgcn_mfma_f32_16x16x32_bf16(wh, ah[xf], acc[nf][xf], 0, 0, 0);
        acc[nf][xf] = __builtin_amdgcn_mfma_f32_16x16x32_bf16(wh, al[xf], acc[nf][xf], 0, 0, 0);
        acc[nf][xf] = __builtin_amdgcn_mfma_f32_16x16x32_bf16(wl, ah[xf], acc[nf][xf], 0, 0, 0);
      }
    }
    if (has) writeA((ks & 1) ^ 1);
    __syncthreads();
  };

  // ---- prologue: stage tile 0 ----
  loadB(0, brA);
  loadA(0);
  writeA(0);
  __syncthreads();

#pragma unroll 1
  for (int ks = 0; ks < KSTEPS; ks += 2) {   // KSTEPS even (64 / 96)
    step(ks, brA, brB);
    step(ks + 1, brB, brA);
  }

  // ---- epilogue: D col = lane&15 -> m, row = (lane>>4)*4+r -> co ----
#pragma unroll
  for (int nf = 0; nf < NFRAG; ++nf) {
    int n0 = nbase + nf * 16 + (l >> 4) * 4;
#pragma unroll
    for (int xf = 0; xf < 4; ++xf) {
      int m = mbase + xf * 16 + rsel;
      int yl = m >> 6, xo = m & 63;
      int yout = y0 * NWX + yl;
#pragma unroll
      for (int r = 0; r < 4; ++r) {
        float v = acc[nf][xf][r] + bias[n0 + r];
        if constexpr (SPLIT_OUT) {  // conv2: ReLU + packed padded store
          if (v < 0.f) v = 0.f;
          outp[((size_t)bb * OC + n0 + r) * OSP + (size_t)(yout + OPAD) * OSR + (xo + OPAD)] =
              packsplit(v);
        } else {                    // conv3: fp32 dense z
          outf[((size_t)bb * OC + n0 + r) * OSP + (size_t)yout * OSR + xo] = v;
        }
      }
    }
  }
}

// ================= embedding norms =================
__global__ void enorm_k(const float* __restrict__ emb, float* __restrict__ enorm) {
  int k = threadIdx.x;
  if (k < 512) {
    float s = 0.f;
#pragma unroll
    for (int d = 0; d < 64; ++d) { float e = emb[k * 64 + d]; s += e * e; }
    enorm[k] = s;
  }
}

// ================= VQ: argmin + quantize(in-place) + hist + sse =================
__global__ __launch_bounds__(256) void vq_k(float* __restrict__ zq,
                                            const float* __restrict__ emb,
                                            const float* __restrict__ enorm,
                                            unsigned* __restrict__ hist,
                                            float* __restrict__ gsse) {
  const int n = blockIdx.x * 256 + threadIdx.x;
  __shared__ unsigned hcnt[512];
  for (int i = threadIdx.x; i < 512; i += 256) hcnt[i] = 0;
  __syncthreads();
  float z[64];
  const float4* zp4 = reinterpret_cast<const float4*>(&zq[(size_t)n * 64]);
#pragma unroll
  for (int d4 = 0; d4 < 16; ++d4) {
    float4 v = zp4[d4];
    z[d4 * 4 + 0] = v.x; z[d4 * 4 + 1] = v.y; z[d4 * 4 + 2] = v.z; z[d4 * 4 + 3] = v.w;
  }
  float best = 1e30f; int bidx = 0;
  for (int k = 0; k < 512; ++k) {
    float dot = 0.f;
    const float* ep = &emb[k * 64];  // uniform -> s_load
#pragma unroll
    for (int d = 0; d < 64; ++d) dot += z[d] * ep[d];
    float dist = enorm[k] - 2.f * dot;
    if (dist < best) { best = dist; bidx = k; }  // strict < : first-min == argmin
  }
  atomicAdd(&hcnt[bidx], 1u);
  float sse = 0.f;
  float4* op4 = reinterpret_cast<float4*>(&zq[(size_t)n * 64]);
  const float4* eb4 = reinterpret_cast<const float4*>(&emb[bidx * 64]);
#pragma unroll
  for (int d4 = 0; d4 < 16; ++d4) {
    float4 q = eb4[d4];
    float dx = q.x - z[d4 * 4 + 0], dy = q.y - z[d4 * 4 + 1];
    float dz = q.z - z[d4 * 4 + 2], dw = q.w - z[d4 * 4 + 3];
    sse += dx * dx + dy * dy + dz * dz + dw * dw;
    op4[d4] = q;
  }
#pragma unroll
  for (int off = 32; off > 0; off >>= 1) sse += __shfl_down(sse, off, 64);
  if ((threadIdx.x & 63) == 0) atomicAdd(gsse, sse);
  __syncthreads();
  for (int i = threadIdx.x; i < 512; i += 256)
    if (hcnt[i]) atomicAdd(&hist[i], hcnt[i]);
}

// ================= finalize =================
__global__ void fin_k(const unsigned* __restrict__ hist,
                      const float* __restrict__ gsse,
                      float* __restrict__ out) {
  __shared__ float red[512];
  int t = threadIdx.x;
  float p = (float)hist[t] * (1.f / 65536.f);
  red[t] = p * logf(p + 1e-10f);
  __syncthreads();
  for (int s = 256; s > 0; s >>= 1) {
    if (t < s) red[t] += red[t + s];
    __syncthreads();
  }
  if (t == 0) {
    out[4194304] = 1.25f * gsse[0] * (1.f / 4194304.f);
    out[4194305] = expf(-red[0]);
  }
}

extern "C" void kernel_launch(void* const* d_in, const int* in_sizes, int n_in,
                              void* d_out, int out_size, void* d_ws, size_t ws_size,
                              hipStream_t stream) {
  const float* x   = (const float*)d_in[0];
  const float* w1  = (const float*)d_in[1];
  const float* b1  = (const float*)d_in[2];
  const float* w2  = (const float*)d_in[3];
  const float* b2  = (const float*)d_in[4];
  const float* w3  = (const float*)d_in[5];
  const float* b3  = (const float*)d_in[6];
  const float* emb = (const float*)d_in[7];
  // decoder weights unused: reference output ignores x_recon

  float* out = (float*)d_out;
  unsigned* wsu = (unsigned*)d_ws;
  unsigned* h1p = wsu + H1P_OFF;
  unsigned* h2p = wsu + H2P_OFF;
  unsigned* wq2 = wsu + WP2_OFF;
  unsigned* wq3 = wsu + WP3_OFF;
  float* enorm = (float*)(wsu + EN_OFF);
  unsigned* hist = wsu + HIST_OFF;
  float* gsse = (float*)(wsu + SSE_OFF);

  hipMemsetAsync(wsu + HIST_OFF, 0, (512 + 1) * sizeof(unsigned), stream);

  pack_wq2_k<<<dim3(2048), dim3(256), 0, stream>>>(w2, wq2);
  pack_wq3_k<<<dim3(768),  dim3(256), 0, stream>>>(w3, wq3);
  halo_k<<<dim3(9408), dim3(256), 0, stream>>>(h1p, h2p);
  enorm_k<<<dim3(1), dim3(512), 0, stream>>>(emb, enorm);

  conv1_k<<<dim3(8, 8, 16), dim3(16, 16), 0, stream>>>(x, w1, b1, h1p);
  // conv2: 128->256, 4x4 s2 p1 ; M=64 (NWX=1,NWC=4), out h2p [66][68] packed+ReLU
  convmm_k<128, 16, 256, 130, 132, 2, 1, 4, 68, 4488, 1, true>
      <<<dim3(1024), dim3(256), 0, stream>>>(h1p, wq2, b2, h2p, nullptr);
  // conv3: 256->64, 3x3 s1 p1 (kw padded to 4) ; M=128 (NWX=2,NWC=2), fp32 z -> d_out
  convmm_k<256, 12, 64, 66, 68, 1, 2, 2, 64, 4096, 0, false>
      <<<dim3(512), dim3(256), 0, stream>>>(h2p, wq3, b3, nullptr, out);

  vq_k<<<dim3(256), dim3(256), 0, stream>>>(out, emb, enorm, hist, gsse);
  fin_k<<<dim3(1), dim3(512), 0, stream>>>(hist, gsse, out);
}